// Round 5
// baseline (299.837 us; speedup 1.0000x reference)
//
#include <hip/hip_runtime.h>
#include <hip/hip_bf16.h>
#include <math.h>

#define BB 65536
#define DD 256
#define KK 10
#define LOG_2PI 1.8378770664093453f

// ---------------------------------------------------------------------------
// Prep kernel: grid = K blocks x D threads.
// Table layout: interleaved float4 PAIRS, indexed by (j,k,s):
//   t4[ ((j*K + k)*16 + s)*2 + 0 ] = iv[d..d+3]      (d = (j*16+s)*4)
//   t4[ ((j*K + k)*16 + s)*2 + 1 ] = -2*mu*iv[d..d+3]
// At fixed (j,k) the 16 lanes read 512B contiguous; all 4 groups of a wave
// read the SAME 512B (broadcast). Single base + small offsets in main loop.
// Also writes per-component constant C[k].
// ---------------------------------------------------------------------------
__global__ __launch_bounds__(DD) void gmvae_prep(
    const float* __restrict__ mu_table,
    const float* __restrict__ logvar_table,
    float* __restrict__ tab,   // 2*K*D floats (20 KB)
    float* __restrict__ C)     // K floats
{
    const int k = blockIdx.x;
    const int d = threadIdx.x;
    const float lv = logvar_table[k * DD + d];
    const float m  = mu_table[k * DD + d];
    const float iv = expf(-lv);          // exact 1.0 when lv==0
    const float a  = m * iv;

    const int f = d >> 2;        // float4 index within row: 0..63
    const int s = f & 15;        // lane-slot 0..15
    const int j = f >> 4;        // 0..3
    const int c = d & 3;
    const int base = (((j * KK + k) * 16 + s) * 2) * 4 + c;
    tab[base]     = iv;
    tab[base + 4] = -2.0f * a;

    // partial for C_k: mu^2*iv + lv
    float p = fmaf(m, a, lv);

    __shared__ float red[4];
    #pragma unroll
    for (int off = 32; off > 0; off >>= 1)
        p += __shfl_down(p, off, 64);
    if ((threadIdx.x & 63) == 0)
        red[threadIdx.x >> 6] = p;
    __syncthreads();
    if (threadIdx.x == 0) {
        const float s2 = (red[0] + red[1]) + (red[2] + red[3]);
        C[k] = -0.5f * (s2 + 256.0f * LOG_2PI) + logf(0.1f);
    }
}

// Sum across the 16-lane DPP "row" using row_ror rotations on the VALU pipe
// (no LDS traffic). After 4 steps every lane in the row holds the total.
// row_ror:n ctrl encoding = 0x120 + n.
template <int CTRL>
__device__ __forceinline__ float dpp_rot_add(float v) {
    const int r = __builtin_amdgcn_update_dpp(
        0, __float_as_int(v), CTRL, 0xF, 0xF, true);
    return v + __int_as_float(r);
}

__device__ __forceinline__ float row_reduce16(float v) {
    v = dpp_rot_add<0x128>(v);   // ror 8
    v = dpp_rot_add<0x124>(v);   // ror 4
    v = dpp_rot_add<0x122>(v);   // ror 2
    v = dpp_rot_add<0x121>(v);   // ror 1
    return v;
}

// ---------------------------------------------------------------------------
// Main kernel: 16 lanes per group, each group handles 4 rows (table loads
// amortized 4x). grid = 1024 blocks x 256 threads = 4096 waves.
// __launch_bounds__(256,4): grid caps occupancy at 4 waves/SIMD anyway, so
// cap VGPRs at 128 to guarantee no scratch spill (R4: 140 VGPR + 25MB spill).
// ---------------------------------------------------------------------------
__global__ __launch_bounds__(256, 4) void gmvae_main(
    const float* __restrict__ q_z,
    const float* __restrict__ tab,
    const float* __restrict__ C,
    float* __restrict__ out)
{
    const int tid = blockIdx.x * 256 + threadIdx.x;
    const int g   = tid >> 4;        // group id: 4 rows each
    const int s   = tid & 15;        // slot within group
    const int r0  = g << 2;          // first row of this group

    const float4* __restrict__ q4  = reinterpret_cast<const float4*>(q_z);
    // single per-lane base: pairs for slot s
    const float4* __restrict__ t4  =
        reinterpret_cast<const float4*>(tab) + s * 2;

    float acc[4][KK];
    #pragma unroll
    for (int r = 0; r < 4; ++r)
        #pragma unroll
        for (int k = 0; k < KK; ++k) acc[r][k] = 0.f;

    #pragma unroll
    for (int j = 0; j < 4; ++j) {
        float4 q[4];
        #pragma unroll
        for (int r = 0; r < 4; ++r)
            q[r] = q4[(size_t)(r0 + r) * 64 + j * 16 + s];
        #pragma unroll
        for (int k = 0; k < KK; ++k) {
            const float4 iv = t4[(j * KK + k) * 32];
            const float4 na = t4[(j * KK + k) * 32 + 1];
            #pragma unroll
            for (int r = 0; r < 4; ++r) {
                acc[r][k] = fmaf(q[r].x, fmaf(iv.x, q[r].x, na.x), acc[r][k]);
                acc[r][k] = fmaf(q[r].y, fmaf(iv.y, q[r].y, na.y), acc[r][k]);
                acc[r][k] = fmaf(q[r].z, fmaf(iv.z, q[r].z, na.z), acc[r][k]);
                acc[r][k] = fmaf(q[r].w, fmaf(iv.w, q[r].w, na.w), acc[r][k]);
            }
        }
    }

    // DPP-reduce each acc[r][k] across the 16-lane group (VALU pipe only);
    // afterwards every lane holds the sum for all 4 rows.
    #pragma unroll
    for (int r = 0; r < 4; ++r)
        #pragma unroll
        for (int k = 0; k < KK; ++k)
            acc[r][k] = fmaf(row_reduce16(acc[r][k]), -0.5f, C[k]);

    // Each lane picks row (s & 3): divergence-free 4-way select.
    const int rm = s & 3;
    float l[KK];
    #pragma unroll
    for (int k = 0; k < KK; ++k) {
        float v = acc[0][k];
        v = (rm == 1) ? acc[1][k] : v;
        v = (rm == 2) ? acc[2][k] : v;
        v = (rm == 3) ? acc[3][k] : v;
        l[k] = v;
    }

    float mx = l[0];
    #pragma unroll
    for (int k = 1; k < KK; ++k) mx = fmaxf(mx, l[k]);

    float e[KK];
    float sum = 0.f;
    #pragma unroll
    for (int k = 0; k < KK; ++k) { e[k] = __expf(l[k] - mx); sum += e[k]; }
    const float inv = __builtin_amdgcn_rcpf(sum);

    int idx = 0;
    float best = l[0];
    #pragma unroll
    for (int k = 1; k < KK; ++k) {
        if (l[k] > best) { best = l[k]; idx = k; }
    }

    if (s < 4) {                       // lane s stores row r0+s
        const int row = r0 + s;
        float2* __restrict__ o1 =
            reinterpret_cast<float2*>(out) + (size_t)row * 5;
        float2* __restrict__ o2 =
            reinterpret_cast<float2*>(out + (size_t)BB * KK) + (size_t)row * 5;
        #pragma unroll
        for (int k = 0; k < 5; ++k)
            o1[k] = make_float2(l[2 * k], l[2 * k + 1]);
        #pragma unroll
        for (int k = 0; k < 5; ++k)
            o2[k] = make_float2(e[2 * k] * inv, e[2 * k + 1] * inv);
        out[(size_t)2 * BB * KK + row] = (float)idx;
    }
}

extern "C" void kernel_launch(void* const* d_in, const int* in_sizes, int n_in,
                              void* d_out, int out_size, void* d_ws, size_t ws_size,
                              hipStream_t stream) {
    const float* q_z    = (const float*)d_in[0];
    const float* mu     = (const float*)d_in[1];
    const float* logvar = (const float*)d_in[2];
    float* out = (float*)d_out;

    float* tab = (float*)d_ws;          // 2*K*D = 5120 floats
    float* C   = tab + 2 * KK * DD;     // 10 floats

    gmvae_prep<<<KK, DD, 0, stream>>>(mu, logvar, tab, C);
    gmvae_main<<<(BB / 4) * 16 / 256, 256, 0, stream>>>(q_z, tab, C, out);
}

// Round 6
// 110.464 us; speedup vs baseline: 2.7144x; 2.7144x over previous
//
#include <hip/hip_runtime.h>
#include <hip/hip_bf16.h>
#include <math.h>

#define BB 65536
#define DD 256
#define KK 10
#define LOG_2PI 1.8378770664093453f
#define ROWS_PB 128          // rows per main block
#define NCHUNK 4             // 64-dim chunks per row

// ---------------------------------------------------------------------------
// Prep: grid = K blocks x 256 threads.
// Table layout (scalar-load friendly): flat = ((c*16 + j)*K + k)*8 + comp,
//   comp 0..3 = iv[d..d+3], comp 4..7 = -2*mu*iv[d..d+3],
// where d = c*64 + j*4. Within main's (c,j,k) loop the address is
// wave-uniform -> s_load into SGPRs. Also writes C[k].
// ---------------------------------------------------------------------------
__global__ __launch_bounds__(DD) void gmvae_prep(
    const float* __restrict__ mu_table,
    const float* __restrict__ logvar_table,
    float* __restrict__ tab,   // 2*K*D floats (20 KB)
    float* __restrict__ C)     // K floats
{
    const int k = blockIdx.x;
    const int d = threadIdx.x;
    const float lv = logvar_table[k * DD + d];
    const float m  = mu_table[k * DD + d];
    const float iv = expf(-lv);          // exact 1.0 when lv==0
    const float a  = m * iv;

    const int c  = d >> 6;
    const int j  = (d >> 2) & 15;
    const int cc = d & 3;
    const int base = ((c * 16 + j) * KK + k) * 8 + cc;
    tab[base]     = iv;
    tab[base + 4] = -2.0f * a;

    float p = fmaf(m, a, lv);            // mu^2*iv + lv
    __shared__ float red[4];
    #pragma unroll
    for (int off = 32; off > 0; off >>= 1)
        p += __shfl_down(p, off, 64);
    if ((threadIdx.x & 63) == 0)
        red[threadIdx.x >> 6] = p;
    __syncthreads();
    if (threadIdx.x == 0) {
        const float s2 = (red[0] + red[1]) + (red[2] + red[3]);
        C[k] = -0.5f * (s2 + 256.0f * LOG_2PI) + logf(0.1f);
    }
}

// ---------------------------------------------------------------------------
// Main: thread = (row, 64-dim chunk). Block = 128 threads = 128 rows.
// grid = 512 row-blocks * 4 chunks = 2048 blocks. q staged via LDS in two
// 32-dim sub-stages ([128][9] float4 = 18 KB -> 8 blocks/CU). Table values
// come from wave-uniform scalar loads. Writes partial sums part[c][k][row].
// Per-thread state ~50 VGPR: no spill (R4/R5 lesson).
// ---------------------------------------------------------------------------
__global__ __launch_bounds__(ROWS_PB) void gmvae_partial(
    const float* __restrict__ q_z,
    const float* __restrict__ tab,
    float* __restrict__ part)
{
    __shared__ float4 lds4[ROWS_PB * 9];   // stride 9 float4 (+1 pad)
    const int tid  = threadIdx.x;
    const int blk  = blockIdx.x;
    const int c    = blk & 3;
    const int row0 = (blk >> 2) * ROWS_PB;

    const float4* __restrict__ q4 = reinterpret_cast<const float4*>(q_z);

    float acc[KK];
    #pragma unroll
    for (int k = 0; k < KK; ++k) acc[k] = 0.f;

    #pragma unroll
    for (int h = 0; h < 2; ++h) {
        if (h) __syncthreads();            // protect LDS before overwrite
        #pragma unroll
        for (int i = 0; i < 8; ++i) {      // stage 128 rows x 8 float4
            const int flat = i * ROWS_PB + tid;
            const int rr = flat >> 3, f4 = flat & 7;
            lds4[rr * 9 + f4] =
                q4[(size_t)(row0 + rr) * 64 + c * 16 + h * 8 + f4];
        }
        __syncthreads();
        #pragma unroll
        for (int j = 0; j < 8; ++j) {
            const float4 q = lds4[tid * 9 + j];
            const float qx2 = q.x * q.x, qy2 = q.y * q.y;
            const float qz2 = q.z * q.z, qw2 = q.w * q.w;
            // wave-uniform table base for (c, h*8+j)
            const float* tp = tab + (size_t)((c * 16 + h * 8 + j) * KK) * 8;
            #pragma unroll
            for (int k = 0; k < KK; ++k) {
                const float4 iv = *reinterpret_cast<const float4*>(tp + k * 8);
                const float4 na = *reinterpret_cast<const float4*>(tp + k * 8 + 4);
                // each FMA reads at most ONE sgpr operand
                acc[k] = fmaf(qx2, iv.x, acc[k]);
                acc[k] = fmaf(q.x, na.x, acc[k]);
                acc[k] = fmaf(qy2, iv.y, acc[k]);
                acc[k] = fmaf(q.y, na.y, acc[k]);
                acc[k] = fmaf(qz2, iv.z, acc[k]);
                acc[k] = fmaf(q.z, na.z, acc[k]);
                acc[k] = fmaf(qw2, iv.w, acc[k]);
                acc[k] = fmaf(q.w, na.w, acc[k]);
            }
        }
    }

    #pragma unroll
    for (int k = 0; k < KK; ++k)           // coalesced dword stores
        part[(size_t)(c * KK + k) * BB + row0 + tid] = acc[k];
}

// ---------------------------------------------------------------------------
// Final: 4 lanes per row (lane = chunk c). Combine chunks via shfl_xor,
// apply -0.5 and C[k], softmax + argmax, stores split across c-lanes.
// grid = B*4 threads = 1024 blocks x 256.
// ---------------------------------------------------------------------------
__global__ __launch_bounds__(256) void gmvae_final(
    const float* __restrict__ part,
    const float* __restrict__ C,
    float* __restrict__ out)
{
    const int t   = blockIdx.x * 256 + threadIdx.x;
    const int c   = t & 3;
    const int row = t >> 2;

    float l[KK];
    #pragma unroll
    for (int k = 0; k < KK; ++k) {
        float v = part[(size_t)(c * KK + k) * BB + row];
        v += __shfl_xor(v, 1, 64);
        v += __shfl_xor(v, 2, 64);
        l[k] = fmaf(v, -0.5f, C[k]);
    }

    float mx = l[0];
    #pragma unroll
    for (int k = 1; k < KK; ++k) mx = fmaxf(mx, l[k]);

    float e[KK];
    float sum = 0.f;
    #pragma unroll
    for (int k = 0; k < KK; ++k) { e[k] = __expf(l[k] - mx); sum += e[k]; }
    const float inv = 1.0f / sum;

    int idx = 0;
    float best = l[0];
    #pragma unroll
    for (int k = 1; k < KK; ++k)
        if (l[k] > best) { best = l[k]; idx = k; }

    if (c == 0) {                              // logits
        float2* __restrict__ o1 = reinterpret_cast<float2*>(out) + (size_t)row * 5;
        #pragma unroll
        for (int k = 0; k < 5; ++k)
            o1[k] = make_float2(l[2 * k], l[2 * k + 1]);
    } else if (c == 1) {                       // q_y
        float2* __restrict__ o2 =
            reinterpret_cast<float2*>(out + (size_t)BB * KK) + (size_t)row * 5;
        #pragma unroll
        for (int k = 0; k < 5; ++k)
            o2[k] = make_float2(e[2 * k] * inv, e[2 * k + 1] * inv);
    } else if (c == 2) {                       // ind
        out[(size_t)2 * BB * KK + row] = (float)idx;
    }
}

extern "C" void kernel_launch(void* const* d_in, const int* in_sizes, int n_in,
                              void* d_out, int out_size, void* d_ws, size_t ws_size,
                              hipStream_t stream) {
    const float* q_z    = (const float*)d_in[0];
    const float* mu     = (const float*)d_in[1];
    const float* logvar = (const float*)d_in[2];
    float* out = (float*)d_out;

    float* tab  = (float*)d_ws;                 // 5120 floats
    float* C    = tab + 5120;                   // 10 floats
    float* part = (float*)d_ws + 8192;          // 4*K*B floats = 10.49 MB

    gmvae_prep<<<KK, DD, 0, stream>>>(mu, logvar, tab, C);
    gmvae_partial<<<(BB / ROWS_PB) * NCHUNK, ROWS_PB, 0, stream>>>(q_z, tab, part);
    gmvae_final<<<(BB * 4) / 256, 256, 0, stream>>>(part, C, out);
}

// Round 7
// 108.933 us; speedup vs baseline: 2.7525x; 1.0141x over previous
//
#include <hip/hip_runtime.h>
#include <hip/hip_bf16.h>
#include <math.h>

#define BB 65536
#define DD 256
#define KK 10
#define LOG_2PI 1.8378770664093453f

// ---------------------------------------------------------------------------
// Prep: grid = K blocks x 256 threads.
// Table layout: tab[(f*K + k)*8 + comp], f = float4 index 0..63 of the dim
// axis; comp 0..3 = iv[d..d+3], comp 4..7 = -2*mu*iv[d..d+3]. In main the
// (f,k) address is wave-uniform -> s_load. Also writes C[k].
// ---------------------------------------------------------------------------
__global__ __launch_bounds__(DD) void gmvae_prep(
    const float* __restrict__ mu_table,
    const float* __restrict__ logvar_table,
    float* __restrict__ tab,   // 2*K*D floats (20 KB)
    float* __restrict__ C)     // K floats
{
    const int k = blockIdx.x;
    const int d = threadIdx.x;
    const float lv = logvar_table[k * DD + d];
    const float m  = mu_table[k * DD + d];
    const float iv = expf(-lv);          // exact 1.0 when lv==0
    const float a  = m * iv;

    const int f    = d >> 2;
    const int comp = d & 3;
    tab[(f * KK + k) * 8 + comp]     = iv;
    tab[(f * KK + k) * 8 + comp + 4] = -2.0f * a;

    float p = fmaf(m, a, lv);            // mu^2*iv + lv
    __shared__ float red[4];
    #pragma unroll
    for (int off = 32; off > 0; off >>= 1)
        p += __shfl_down(p, off, 64);
    if ((threadIdx.x & 63) == 0)
        red[threadIdx.x >> 6] = p;
    __syncthreads();
    if (threadIdx.x == 0) {
        const float s2 = (red[0] + red[1]) + (red[2] + red[3]);
        C[k] = -0.5f * (s2 + 256.0f * LOG_2PI) + logf(0.1f);
    }
}

// ---------------------------------------------------------------------------
// Fused main: block = 256 threads = 4 waves; block owns 64 rows.
// Wave c owns dim-chunk c: per dim-half h, wave c processes float4 indices
// f = h*32 + c*8 + j (j=0..7). Table address is wave-uniform BY CONSTRUCTION
// (c via readfirstlane) -> scalar s_load, zero VMEM issue for coefficients.
// q is staged to LDS per half (64 rows x 32 f4, coalesced), each lane then
// ds_reads its own row's 8 float4. Cross-wave combine + softmax epilogue via
// LDS aliased onto the q buffer. Per-thread state ~30 VGPR: no spill.
// grid = B/64 = 1024 blocks.
// ---------------------------------------------------------------------------
__global__ __launch_bounds__(256) void gmvae_main(
    const float* __restrict__ q_z,
    const float* __restrict__ tab,
    const float* __restrict__ C,
    float* __restrict__ out)
{
    __shared__ float4 lds4[64 * 33];               // 33 KB (row stride 33: pad)
    float* comb = reinterpret_cast<float*>(lds4);  // aliased after q use

    const int t    = threadIdx.x;
    const int r    = t & 63;                                   // lane = row
    const int c    = __builtin_amdgcn_readfirstlane(t >> 6);   // wave id (SGPR)
    const int row0 = blockIdx.x * 64;

    const float4* __restrict__ q4 = reinterpret_cast<const float4*>(q_z);

    float acc[KK];
    #pragma unroll
    for (int k = 0; k < KK; ++k) acc[k] = 0.f;

    #pragma unroll
    for (int h = 0; h < 2; ++h) {
        if (h) __syncthreads();        // protect LDS before restage
        // stage: 64 rows x 32 float4 (half of each row), fully coalesced
        #pragma unroll
        for (int i = 0; i < 8; ++i) {
            const int flat = i * 256 + t;
            const int rr = flat >> 5, ff = flat & 31;
            lds4[rr * 33 + ff] = q4[(size_t)(row0 + rr) * 64 + h * 32 + ff];
        }
        __syncthreads();

        #pragma unroll
        for (int j = 0; j < 8; ++j) {
            const float4 q = lds4[r * 33 + c * 8 + j];
            const float qx2 = q.x * q.x, qy2 = q.y * q.y;
            const float qz2 = q.z * q.z, qw2 = q.w * q.w;
            // wave-uniform table base (dwords): f = h*32 + c*8 + j
            const int toff = __builtin_amdgcn_readfirstlane(
                ((h * 32 + c * 8 + j) * KK) * 8);
            const float* tp = tab + toff;
            #pragma unroll
            for (int k = 0; k < KK; ++k) {
                const float4 iv = *reinterpret_cast<const float4*>(tp + k * 8);
                const float4 na = *reinterpret_cast<const float4*>(tp + k * 8 + 4);
                acc[k] = fmaf(qx2, iv.x, acc[k]);
                acc[k] = fmaf(q.x, na.x, acc[k]);
                acc[k] = fmaf(qy2, iv.y, acc[k]);
                acc[k] = fmaf(q.y, na.y, acc[k]);
                acc[k] = fmaf(qz2, iv.z, acc[k]);
                acc[k] = fmaf(q.z, na.z, acc[k]);
                acc[k] = fmaf(qw2, iv.w, acc[k]);
                acc[k] = fmaf(q.w, na.w, acc[k]);
            }
        }
    }

    // cross-wave combine: comb[t][k] (stride 11: odd -> conflict-free)
    __syncthreads();                   // all q reads done; safe to alias
    #pragma unroll
    for (int k = 0; k < KK; ++k)
        comb[t * 11 + k] = acc[k];
    __syncthreads();

    if (t < 64) {                      // wave 0 epilogue: row = row0 + r
        float l[KK];
        #pragma unroll
        for (int k = 0; k < KK; ++k) {
            const float v = ((comb[(r)*11 + k]       + comb[(64 + r) * 11 + k]) +
                             (comb[(128 + r) * 11 + k] + comb[(192 + r) * 11 + k]));
            l[k] = fmaf(v, -0.5f, C[k]);
        }

        float mx = l[0];
        #pragma unroll
        for (int k = 1; k < KK; ++k) mx = fmaxf(mx, l[k]);

        float e[KK];
        float sum = 0.f;
        #pragma unroll
        for (int k = 0; k < KK; ++k) { e[k] = __expf(l[k] - mx); sum += e[k]; }
        const float inv = 1.0f / sum;

        int idx = 0;
        float best = l[0];
        #pragma unroll
        for (int k = 1; k < KK; ++k)
            if (l[k] > best) { best = l[k]; idx = k; }

        const int row = row0 + r;
        float2* __restrict__ o1 =
            reinterpret_cast<float2*>(out) + (size_t)row * 5;
        float2* __restrict__ o2 =
            reinterpret_cast<float2*>(out + (size_t)BB * KK) + (size_t)row * 5;
        #pragma unroll
        for (int k = 0; k < 5; ++k)
            o1[k] = make_float2(l[2 * k], l[2 * k + 1]);
        #pragma unroll
        for (int k = 0; k < 5; ++k)
            o2[k] = make_float2(e[2 * k] * inv, e[2 * k + 1] * inv);
        out[(size_t)2 * BB * KK + row] = (float)idx;
    }
}

extern "C" void kernel_launch(void* const* d_in, const int* in_sizes, int n_in,
                              void* d_out, int out_size, void* d_ws, size_t ws_size,
                              hipStream_t stream) {
    const float* q_z    = (const float*)d_in[0];
    const float* mu     = (const float*)d_in[1];
    const float* logvar = (const float*)d_in[2];
    float* out = (float*)d_out;

    float* tab = (float*)d_ws;          // 5120 floats
    float* C   = tab + 5120;            // 10 floats

    gmvae_prep<<<KK, DD, 0, stream>>>(mu, logvar, tab, C);
    gmvae_main<<<BB / 64, 256, 0, stream>>>(q_z, tab, C, out);
}

// Round 8
// 107.353 us; speedup vs baseline: 2.7930x; 1.0147x over previous
//
#include <hip/hip_runtime.h>
#include <hip/hip_bf16.h>
#include <math.h>

#define BB 65536
#define DD 256
#define KK 10
#define LOG_2PI 1.8378770664093453f

// ---------------------------------------------------------------------------
// Prep: grid = K blocks x 256 threads.
// Table layout: tab[(f*K + k)*8 + comp], f = float4 index 0..63 of the dim
// axis; comp 0..3 = iv[d..d+3], comp 4..7 = -2*mu*iv[d..d+3]. In main the
// (f,k) address is wave-uniform -> s_load. Also writes C[k].
// ---------------------------------------------------------------------------
__global__ __launch_bounds__(DD) void gmvae_prep(
    const float* __restrict__ mu_table,
    const float* __restrict__ logvar_table,
    float* __restrict__ tab,   // 2*K*D floats (20 KB)
    float* __restrict__ C)     // K floats
{
    const int k = blockIdx.x;
    const int d = threadIdx.x;
    const float lv = logvar_table[k * DD + d];
    const float m  = mu_table[k * DD + d];
    const float iv = expf(-lv);          // exact 1.0 when lv==0
    const float a  = m * iv;

    const int f    = d >> 2;
    const int comp = d & 3;
    tab[(f * KK + k) * 8 + comp]     = iv;
    tab[(f * KK + k) * 8 + comp + 4] = -2.0f * a;

    float p = fmaf(m, a, lv);            // mu^2*iv + lv
    __shared__ float red[4];
    #pragma unroll
    for (int off = 32; off > 0; off >>= 1)
        p += __shfl_down(p, off, 64);
    if ((threadIdx.x & 63) == 0)
        red[threadIdx.x >> 6] = p;
    __syncthreads();
    if (threadIdx.x == 0) {
        const float s2 = (red[0] + red[1]) + (red[2] + red[3]);
        C[k] = -0.5f * (s2 + 256.0f * LOG_2PI) + logf(0.1f);
    }
}

// ---------------------------------------------------------------------------
// Fused main, 4-stage software pipeline. Block = 256 threads = 4 waves,
// owns 64 rows. Stage s covers f4 indices s*16..s*16+15 of every row.
// Pipeline: global loads for stage s+1 are issued BEFORE compute(s), their
// ds_write lands after compute(s) -> HBM latency hides under FMA work.
// Double-buffered LDS, 1 barrier/stage; buffer parity (s+1)&1 was last read
// by compute(s-1) which precedes the previous barrier -> safe.
// Wave c computes f4 = s*16 + c*4 + jj -> table offset wave-uniform ->
// scalar s_load for all coefficients (zero VMEM issue).
// Per-thread state ~55 VGPR: no spill (R4/R5 lesson).
// grid = B/64 = 1024 blocks; LDS 34.8 KB -> 4 blocks/CU.
// ---------------------------------------------------------------------------
__global__ __launch_bounds__(256) void gmvae_main(
    const float* __restrict__ q_z,
    const float* __restrict__ tab,
    const float* __restrict__ C,
    float* __restrict__ out)
{
    __shared__ float4 buf[2 * 64 * 17];            // 34.8 KB, row stride 17
    float* comb = reinterpret_cast<float*>(buf);   // aliased in epilogue

    const int t    = threadIdx.x;
    const int r    = t & 63;                                   // lane = row
    const int c    = __builtin_amdgcn_readfirstlane(t >> 6);   // wave id
    const int row0 = blockIdx.x * 64;

    const float4* __restrict__ q4 = reinterpret_cast<const float4*>(q_z);

    // thread's staging slice: 4 f4 per stage; flat = i*256 + t
    const int rr0 = t >> 4;          // rr for i=0 (rr = (i*256+t)>>4 = i*16 + t>>4)
    const int ff  = t & 15;

    float acc[KK];
    #pragma unroll
    for (int k = 0; k < KK; ++k) acc[k] = 0.f;

    float4 v[4];
    // ---- prologue: load + stage s=0
    #pragma unroll
    for (int i = 0; i < 4; ++i)
        v[i] = q4[(size_t)(row0 + i * 16 + rr0) * 64 + 0 * 16 + ff];
    #pragma unroll
    for (int i = 0; i < 4; ++i)
        buf[(i * 16 + rr0) * 17 + ff] = v[i];
    __syncthreads();

    #pragma unroll
    for (int s = 0; s < 4; ++s) {
        // issue next stage's global loads (no wait; hides under compute)
        if (s < 3) {
            #pragma unroll
            for (int i = 0; i < 4; ++i)
                v[i] = q4[(size_t)(row0 + i * 16 + rr0) * 64 + (s + 1) * 16 + ff];
        }

        // compute stage s from LDS buf[s&1]
        const float4* bp = buf + (s & 1) * (64 * 17) + r * 17 + c * 4;
        #pragma unroll
        for (int jj = 0; jj < 4; ++jj) {
            const float4 q = bp[jj];
            const float qx2 = q.x * q.x, qy2 = q.y * q.y;
            const float qz2 = q.z * q.z, qw2 = q.w * q.w;
            const int toff = __builtin_amdgcn_readfirstlane(
                ((s * 16 + c * 4 + jj) * KK) * 8);
            const float* tp = tab + toff;
            #pragma unroll
            for (int k = 0; k < KK; ++k) {
                const float4 iv = *reinterpret_cast<const float4*>(tp + k * 8);
                const float4 na = *reinterpret_cast<const float4*>(tp + k * 8 + 4);
                acc[k] = fmaf(qx2, iv.x, acc[k]);
                acc[k] = fmaf(q.x, na.x, acc[k]);
                acc[k] = fmaf(qy2, iv.y, acc[k]);
                acc[k] = fmaf(q.y, na.y, acc[k]);
                acc[k] = fmaf(qz2, iv.z, acc[k]);
                acc[k] = fmaf(q.z, na.z, acc[k]);
                acc[k] = fmaf(qw2, iv.w, acc[k]);
                acc[k] = fmaf(q.w, na.w, acc[k]);
            }
        }

        // stage s+1 into the other buffer, one barrier per stage
        if (s < 3) {
            float4* wp = buf + ((s + 1) & 1) * (64 * 17);
            #pragma unroll
            for (int i = 0; i < 4; ++i)
                wp[(i * 16 + rr0) * 17 + ff] = v[i];
            __syncthreads();
        }
    }

    // cross-wave combine: comb[t][k] (stride 11, odd -> conflict-free)
    __syncthreads();                   // all LDS q reads done; safe to alias
    #pragma unroll
    for (int k = 0; k < KK; ++k)
        comb[t * 11 + k] = acc[k];
    __syncthreads();

    if (t < 64) {                      // wave 0 epilogue: row = row0 + r
        float l[KK];
        #pragma unroll
        for (int k = 0; k < KK; ++k) {
            const float vsum =
                ((comb[r * 11 + k]         + comb[(64 + r) * 11 + k]) +
                 (comb[(128 + r) * 11 + k] + comb[(192 + r) * 11 + k]));
            l[k] = fmaf(vsum, -0.5f, C[k]);
        }

        float mx = l[0];
        #pragma unroll
        for (int k = 1; k < KK; ++k) mx = fmaxf(mx, l[k]);

        float e[KK];
        float sum = 0.f;
        #pragma unroll
        for (int k = 0; k < KK; ++k) { e[k] = __expf(l[k] - mx); sum += e[k]; }
        const float inv = 1.0f / sum;

        int idx = 0;
        float best = l[0];
        #pragma unroll
        for (int k = 1; k < KK; ++k)
            if (l[k] > best) { best = l[k]; idx = k; }

        const int row = row0 + r;
        float2* __restrict__ o1 =
            reinterpret_cast<float2*>(out) + (size_t)row * 5;
        float2* __restrict__ o2 =
            reinterpret_cast<float2*>(out + (size_t)BB * KK) + (size_t)row * 5;
        #pragma unroll
        for (int k = 0; k < 5; ++k)
            o1[k] = make_float2(l[2 * k], l[2 * k + 1]);
        #pragma unroll
        for (int k = 0; k < 5; ++k)
            o2[k] = make_float2(e[2 * k] * inv, e[2 * k + 1] * inv);
        out[(size_t)2 * BB * KK + row] = (float)idx;
    }
}

extern "C" void kernel_launch(void* const* d_in, const int* in_sizes, int n_in,
                              void* d_out, int out_size, void* d_ws, size_t ws_size,
                              hipStream_t stream) {
    const float* q_z    = (const float*)d_in[0];
    const float* mu     = (const float*)d_in[1];
    const float* logvar = (const float*)d_in[2];
    float* out = (float*)d_out;

    float* tab = (float*)d_ws;          // 5120 floats
    float* C   = tab + 5120;            // 10 floats

    gmvae_prep<<<KK, DD, 0, stream>>>(mu, logvar, tab, C);
    gmvae_main<<<BB / 64, 256, 0, stream>>>(q_z, tab, C, out);
}

// Round 9
// 103.954 us; speedup vs baseline: 2.8843x; 1.0327x over previous
//
#include <hip/hip_runtime.h>
#include <hip/hip_bf16.h>
#include <math.h>

#define BB 65536
#define DD 256
#define KK 10
#define LOG_2PI 1.8378770664093453f

// ---------------------------------------------------------------------------
// Prep: grid = K blocks x 256 threads.
// Layout for VGPR-resident slices: wave c (dim chunk c) owns dwords
// [c*1280, (c+1)*1280). Within a slice, float4 index
//   idx_f4 = ((s*4 + jj)*K + k)*2 + half   (half: 0=iv, 1=na)
// where the f4 covered is global f = s*16 + c*4 + jj (dims d=4f..4f+3).
// Main loads slice f4 #(i*64 + lane) into w[i] (i=0..4) -> hot loop reads
// via v_readlane (constant lane after unroll). Also writes C[k].
// ---------------------------------------------------------------------------
__global__ __launch_bounds__(DD) void gmvae_prep(
    const float* __restrict__ mu_table,
    const float* __restrict__ logvar_table,
    float* __restrict__ tab,   // 2*K*D floats (20 KB)
    float* __restrict__ C)     // K floats
{
    const int k = blockIdx.x;
    const int d = threadIdx.x;
    const float lv = logvar_table[k * DD + d];
    const float m  = mu_table[k * DD + d];
    const float iv = expf(-lv);          // exact 1.0 when lv==0
    const float a  = m * iv;

    const int f    = d >> 2;             // global f4 index 0..63
    const int s    = f >> 4;             // stage 0..3
    const int c    = (f >> 2) & 3;       // wave chunk 0..3
    const int jj   = f & 3;              // f4 within (s,c)
    const int comp = d & 3;
    const int idx_f4 = ((s * 4 + jj) * KK + k) * 2;   // iv slot
    const int base   = c * 1280 + idx_f4 * 4 + comp;
    tab[base]     = iv;                  // half 0
    tab[base + 4] = -2.0f * a;           // half 1 (next f4)

    float p = fmaf(m, a, lv);            // mu^2*iv + lv
    __shared__ float red[4];
    #pragma unroll
    for (int off = 32; off > 0; off >>= 1)
        p += __shfl_down(p, off, 64);
    if ((threadIdx.x & 63) == 0)
        red[threadIdx.x >> 6] = p;
    __syncthreads();
    if (threadIdx.x == 0) {
        const float s2 = (red[0] + red[1]) + (red[2] + red[3]);
        C[k] = -0.5f * (s2 + 256.0f * LOG_2PI) + logf(0.1f);
    }
}

__device__ __forceinline__ float rl(float v, int lane) {
    return __int_as_float(__builtin_amdgcn_readlane(__float_as_int(v), lane));
}

// ---------------------------------------------------------------------------
// Fused main. Block = 256 threads = 4 waves, 64 rows. Wave c owns dim-chunk
// c. Coefficients: wave's 1280-dword slice loaded ONCE into w[0..4] (float4
// per lane, 20 VGPRs), broadcast in the hot loop via v_readlane -> SGPR ->
// FMA (zero memory traffic, no s_load lgkmcnt batches — the R8 stall).
// q pipeline: R8's 4-stage double-buffered LDS staging (1 barrier/stage).
// grid = B/64 = 1024 blocks; LDS 34.8 KB -> 4 blocks/CU.
// ---------------------------------------------------------------------------
__global__ __launch_bounds__(256) void gmvae_main(
    const float* __restrict__ q_z,
    const float* __restrict__ tab,
    const float* __restrict__ C,
    float* __restrict__ out)
{
    __shared__ float4 buf[2 * 64 * 17];            // 34.8 KB, row stride 17
    float* comb = reinterpret_cast<float*>(buf);   // aliased in epilogue

    const int t    = threadIdx.x;
    const int r    = t & 63;                                   // lane = row
    const int c    = __builtin_amdgcn_readfirstlane(t >> 6);   // wave id
    const int row0 = blockIdx.x * 64;

    const float4* __restrict__ q4 = reinterpret_cast<const float4*>(q_z);

    // one-time coefficient slice load: slice f4 #(i*64 + r) -> w[i]
    const float4* __restrict__ t4 =
        reinterpret_cast<const float4*>(tab) + c * 320;
    float4 w[5];
    #pragma unroll
    for (int i = 0; i < 5; ++i)
        w[i] = t4[i * 64 + r];

    // thread's staging slice: 4 f4 per stage
    const int rr0 = t >> 4;
    const int ff  = t & 15;

    float acc[KK];
    #pragma unroll
    for (int k = 0; k < KK; ++k) acc[k] = 0.f;

    float4 v[4];
    // ---- prologue: load + stage s=0
    #pragma unroll
    for (int i = 0; i < 4; ++i)
        v[i] = q4[(size_t)(row0 + i * 16 + rr0) * 64 + 0 * 16 + ff];
    #pragma unroll
    for (int i = 0; i < 4; ++i)
        buf[(i * 16 + rr0) * 17 + ff] = v[i];
    __syncthreads();

    #pragma unroll
    for (int s = 0; s < 4; ++s) {
        // issue next stage's global loads (hide under compute)
        if (s < 3) {
            #pragma unroll
            for (int i = 0; i < 4; ++i)
                v[i] = q4[(size_t)(row0 + i * 16 + rr0) * 64 + (s + 1) * 16 + ff];
        }

        // compute stage s from LDS buf[s&1]; coefficients via readlane
        const float4* bp = buf + (s & 1) * (64 * 17) + r * 17 + c * 4;
        #pragma unroll
        for (int jj = 0; jj < 4; ++jj) {
            const float4 q = bp[jj];
            const float qx2 = q.x * q.x, qy2 = q.y * q.y;
            const float qz2 = q.z * q.z, qw2 = q.w * q.w;
            #pragma unroll
            for (int k = 0; k < KK; ++k) {
                const int flat = ((s * 4 + jj) * KK + k) * 2;  // iv f4 slot
                const int i = flat >> 6;
                const int L = flat & 63;                       // na at L+1
                const float4 wv = w[i];
                acc[k] = fmaf(qx2, rl(wv.x, L),     acc[k]);
                acc[k] = fmaf(q.x, rl(wv.x, L + 1), acc[k]);
                acc[k] = fmaf(qy2, rl(wv.y, L),     acc[k]);
                acc[k] = fmaf(q.y, rl(wv.y, L + 1), acc[k]);
                acc[k] = fmaf(qz2, rl(wv.z, L),     acc[k]);
                acc[k] = fmaf(q.z, rl(wv.z, L + 1), acc[k]);
                acc[k] = fmaf(qw2, rl(wv.w, L),     acc[k]);
                acc[k] = fmaf(q.w, rl(wv.w, L + 1), acc[k]);
            }
        }

        // stage s+1 into the other buffer, one barrier per stage
        if (s < 3) {
            float4* wp = buf + ((s + 1) & 1) * (64 * 17);
            #pragma unroll
            for (int i = 0; i < 4; ++i)
                wp[(i * 16 + rr0) * 17 + ff] = v[i];
            __syncthreads();
        }
    }

    // cross-wave combine: comb[t][k] (stride 11, odd -> conflict-free)
    __syncthreads();                   // all LDS q reads done; safe to alias
    #pragma unroll
    for (int k = 0; k < KK; ++k)
        comb[t * 11 + k] = acc[k];
    __syncthreads();

    if (t < 64) {                      // wave 0 epilogue: row = row0 + r
        float l[KK];
        #pragma unroll
        for (int k = 0; k < KK; ++k) {
            const float vsum =
                ((comb[r * 11 + k]         + comb[(64 + r) * 11 + k]) +
                 (comb[(128 + r) * 11 + k] + comb[(192 + r) * 11 + k]));
            l[k] = fmaf(vsum, -0.5f, C[k]);
        }

        float mx = l[0];
        #pragma unroll
        for (int k = 1; k < KK; ++k) mx = fmaxf(mx, l[k]);

        float e[KK];
        float sum = 0.f;
        #pragma unroll
        for (int k = 0; k < KK; ++k) { e[k] = __expf(l[k] - mx); sum += e[k]; }
        const float inv = 1.0f / sum;

        int idx = 0;
        float best = l[0];
        #pragma unroll
        for (int k = 1; k < KK; ++k)
            if (l[k] > best) { best = l[k]; idx = k; }

        const int row = row0 + r;
        float2* __restrict__ o1 =
            reinterpret_cast<float2*>(out) + (size_t)row * 5;
        float2* __restrict__ o2 =
            reinterpret_cast<float2*>(out + (size_t)BB * KK) + (size_t)row * 5;
        #pragma unroll
        for (int k = 0; k < 5; ++k)
            o1[k] = make_float2(l[2 * k], l[2 * k + 1]);
        #pragma unroll
        for (int k = 0; k < 5; ++k)
            o2[k] = make_float2(e[2 * k] * inv, e[2 * k + 1] * inv);
        out[(size_t)2 * BB * KK + row] = (float)idx;
    }
}

extern "C" void kernel_launch(void* const* d_in, const int* in_sizes, int n_in,
                              void* d_out, int out_size, void* d_ws, size_t ws_size,
                              hipStream_t stream) {
    const float* q_z    = (const float*)d_in[0];
    const float* mu     = (const float*)d_in[1];
    const float* logvar = (const float*)d_in[2];
    float* out = (float*)d_out;

    float* tab = (float*)d_ws;          // 5120 floats
    float* C   = tab + 5120;            // 10 floats

    gmvae_prep<<<KK, DD, 0, stream>>>(mu, logvar, tab, C);
    gmvae_main<<<BB / 64, 256, 0, stream>>>(q_z, tab, C, out);
}